// Round 11
// baseline (382.216 us; speedup 1.0000x reference)
//
#include <hip/hip_runtime.h>
#include <hip/hip_bf16.h>
#include <hip/hip_fp16.h>

typedef unsigned short u16;
typedef __attribute__((ext_vector_type(8))) short short8;
typedef __attribute__((ext_vector_type(4))) float floatx4;

#define DEVI static __device__ __forceinline__

DEVI float bf2f(u16 b) { return __uint_as_float(((unsigned)b) << 16); }
DEVI u16 f2bf(float f) {
  __hip_bfloat16 h = __float2bfloat16(f);
  u16 u; __builtin_memcpy(&u, &h, 2); return u;
}
DEVI u16 f2h(float f) {
  __half h = __float2half(f);
  u16 u; __builtin_memcpy(&u, &h, 2); return u;
}

// async global->LDS, 16B per lane; LDS dest = wave-uniform base + lane*16
DEVI void async_ld16(const u16* g, u16* l) {
  __builtin_amdgcn_global_load_lds(
      (const __attribute__((address_space(1))) unsigned int*)g,
      (__attribute__((address_space(3))) unsigned int*)l, 16, 0, 0);
}

// DPP cross-lane add on float (VALU pipe)
template <int CTRL>
DEVI float dpp_add_f(float v) {
  int i; __builtin_memcpy(&i, &v, 4);
  int p = __builtin_amdgcn_update_dpp(0, i, CTRL, 0xF, 0xF, false);
  float pv; __builtin_memcpy(&pv, &p, 4);
  return v + pv;
}

// head-major permutation: feature f (= d*8+h) -> c' = h*64+d
DEVI int hperm(int f) { return ((f & 7) << 6) | (f >> 3); }

// 4x half2 as named fields (NO element address-taking: keeps SROA able to promote
// everything to registers). v8 tested (256,2) on the OLD int4-reinterpret style and
// saw no VGPR change; this is the first (256,2) x H4-style combination.
struct H4 { __half2 a, b, c, d; };
DEVI H4 toH4(const int4 v) { H4 r; __builtin_memcpy(&r, &v, 16); return r; }
DEVI int4 fromH4(const H4 x) { int4 r; __builtin_memcpy(&r, &x, 16); return r; }

// ---------------- weight transpose + fp32->bf16: dst[C][R] = bf16(src[R][C]^T) ----------------
struct TransArgs {
  const float* src[10];
  u16* dst[10];
  int R[10];
  int C[10];
};

__global__ __launch_bounds__(256) void transpose_k(TransArgs t) {
  const int z = blockIdx.z;
  const float* __restrict__ src = t.src[z];
  u16* __restrict__ dst = t.dst[z];
  const int R = t.R[z], C = t.C[z];
  const int c0 = blockIdx.x * 32, r0 = blockIdx.y * 32;
  if (c0 >= C || r0 >= R) return;
  __shared__ float tile[32][33];
  const int tx = threadIdx.x & 31, ty = threadIdx.x >> 5;
  for (int i = ty; i < 32; i += 8)
    tile[i][tx] = src[(size_t)(r0 + i) * C + c0 + tx];
  __syncthreads();
  for (int i = ty; i < 32; i += 8) {
    const int f = r0 + tx;
    const int fi = (z == 9) ? hperm(f) : f;
    dst[(size_t)(c0 + i) * R + fi] = f2bf(tile[tx][i]);
  }
}

// ---------------- fp32 -> bf16 convert for KEY/QUERY/VALUE ----------------
struct ConvArgs {
  const float* src[3];
  u16* dst[3];
};

__global__ __launch_bounds__(256) void conv_k(ConvArgs c) {
  const int z = blockIdx.z;
  const float* __restrict__ src = c.src[z];
  u16* __restrict__ dst = c.dst[z];
  const size_t i = ((size_t)blockIdx.x * 256 + threadIdx.x) * 8;
  const float4 f0 = *(const float4*)(src + i);
  const float4 f1 = *(const float4*)(src + i + 4);
  u16 tmp[8] = {f2bf(f0.x), f2bf(f0.y), f2bf(f0.z), f2bf(f0.w),
                f2bf(f1.x), f2bf(f1.y), f2bf(f1.z), f2bf(f1.w)};
  int4 t; __builtin_memcpy(&t, tmp, 16);
  *(int4*)(dst + i) = t;
}

// ------------- GEMM 128x128 tile, async global->LDS staging (R10, measured -9.5us) -------------
struct GemmArgs {
  const u16* A[3];
  const u16* WT[3];
  const float* bias[3];
  void* C[3];
};

__global__ __launch_bounds__(256, 3) void gemm128(GemmArgs ga, int M, int N, int K,
                                                  int relu, int c_mode, int out_perm) {
  const int z = blockIdx.z;
  const u16* __restrict__ A = ga.A[z];
  const u16* __restrict__ WT = ga.WT[z];
  const float* __restrict__ bias = ga.bias[z];
  void* __restrict__ C = ga.C[z];

  __shared__ u16 As[128 * 64];
  __shared__ u16 Bs[128 * 64];

  const int tid = threadIdx.x;
  const int lane = tid & 63;
  const int wave = tid >> 6;
  const int wm = wave >> 1, wn = wave & 1;
  const int mb = blockIdx.y, nb = blockIdx.x;

  floatx4 acc[4][4];
#pragma unroll
  for (int mi = 0; mi < 4; ++mi)
#pragma unroll
    for (int ni = 0; ni < 4; ++ni) acc[mi][ni] = floatx4{0.f, 0.f, 0.f, 0.f};

  // staging: lane covers row (lane>>3) of an 8-row strip, phys granule (lane&7);
  // global column granule = phys ^ (row&7)
  const int g = (lane & 7) ^ ((lane >> 3) & 7);
  const int srow = lane >> 3;
  const size_t aRowBase = (size_t)(mb * 128 + wave * 32 + srow) * K + g * 8;
  const size_t bRowBase = (size_t)(nb * 128 + wave * 32 + srow) * K + g * 8;

  for (int k0 = 0; k0 < K; k0 += 64) {
    __syncthreads();
#pragma unroll
    for (int it = 0; it < 4; ++it) {
      async_ld16(A + aRowBase + (size_t)it * 8 * K + k0, As + (wave * 32 + it * 8) * 64);
      async_ld16(WT + bRowBase + (size_t)it * 8 * K + k0, Bs + (wave * 32 + it * 8) * 64);
    }
    __syncthreads();
#pragma unroll
    for (int ks = 0; ks < 2; ++ks) {
      const int phys = ((ks * 4 + (lane >> 4)) ^ (lane & 7)) * 8;
      short8 af[4], bf[4];
#pragma unroll
      for (int i = 0; i < 4; ++i) {
        const int m = wm * 64 + i * 16 + (lane & 15);
        const int n = wn * 64 + i * 16 + (lane & 15);
        af[i] = *(const short8*)(As + m * 64 + phys);
        bf[i] = *(const short8*)(Bs + n * 64 + phys);
      }
#pragma unroll
      for (int mi = 0; mi < 4; ++mi)
#pragma unroll
        for (int ni = 0; ni < 4; ++ni)
          acc[mi][ni] = __builtin_amdgcn_mfma_f32_16x16x32_bf16(af[mi], bf[ni], acc[mi][ni], 0, 0, 0);
    }
  }

  // C/D layout: col = lane&15, row = (lane>>4)*4 + reg
#pragma unroll
  for (int mi = 0; mi < 4; ++mi)
#pragma unroll
    for (int ni = 0; ni < 4; ++ni) {
      const int col = nb * 128 + wn * 64 + ni * 16 + (lane & 15);
      const float bv = bias[col];
      const int colw = out_perm ? hperm(col) : col;
      const floatx4 v = acc[mi][ni];
#pragma unroll
      for (int r = 0; r < 4; ++r) {
        const int row = mb * 128 + wm * 64 + mi * 16 + (lane >> 4) * 4 + r;
        float x = v[r] + bv;
        if (relu) x = fmaxf(x, 0.f);
        if (c_mode == 1)      ((float*)C)[(size_t)row * N + colw] = x;
        else if (c_mode == 2) ((u16*)C)[(size_t)row * N + colw] = f2h(x);
        else                  ((u16*)C)[(size_t)row * N + colw] = f2bf(x);
      }
    }
}

// -------- fused attention v15: v14 core + (256,2) reg budget + 8-way key split --------
// Evidence: v12/v13/v14 at 2/3/4 waves per SIMD all land 186-202us, and halving LDS
// reads bought only 7us -> neither occupancy nor LDS binds; the executed stream does
// (~150us busy vs ~68us static floor). VGPR_Count=84 with 128+ live regs of state =>
// hidden AGPR-shuttle / rematerialization overhead. (256,2) gives a 256-reg budget so
// the H4 state can allocate architecturally (v8's (256,2) null was on the SROA-hostile
// int4 style). sp=8: 2048 waves = exactly 2/SIMD x 1024 SIMDs (one resident batch,
// no tail) and halves partial traffic.
__global__ __launch_bounds__(256, 2) void attn_kernel(const u16* __restrict__ Km,
                                                      const u16* __restrict__ Qm,
                                                      const u16* __restrict__ Vm,
                                                      u16* __restrict__ partial) {
  // per wave: 2 buffers x (2 K-rows + 2 V-rows) = 4096 halfs = 8KB; block = 32KB
  __shared__ alignas(16) u16 lds[4 * 4096];

  const int tid = threadIdx.x;
  const int lane = tid & 63;
  const int wave = tid >> 6;
  const int wid = blockIdx.x * 4 + wave;      // 0..2047
  const int qt = wid & 63;                    // 64 q-tiles of 16 rows
  const int sp = (wid >> 6) & 7;              // 8-way key split
  const int b = wid >> 9;
  const int j0 = qt * 16;

  const int qg = lane >> 4;
  const int h = (lane >> 1) & 7;
  const int half = lane & 1;

  int grans[4];
#pragma unroll
  for (int pi = 0; pi < 4; ++pi)
    grans[pi] = h * 8 + half * 4 + ((pi + h) & 3);

  // Q into registers: 4 queries x 4 granules (rotated order), H4 fields
  H4 Qh[4][4];
#pragma unroll
  for (int qi = 0; qi < 4; ++qi) {
    const u16* qrow = Qm + (size_t)(b * 1024 + j0 + qg + qi * 4) * 512;
#pragma unroll
    for (int pi = 0; pi < 4; ++pi)
      Qh[qi][pi] = toH4(*(const int4*)(qrow + grans[pi] * 8));
  }

  const __half2 z2 = __float2half2_rn(0.f);
  H4 o[4][4];
#pragma unroll
  for (int qi = 0; qi < 4; ++qi)
#pragma unroll
    for (int pi = 0; pi < 4; ++pi) { o[qi][pi].a = z2; o[qi][pi].b = z2; o[qi][pi].c = z2; o[qi][pi].d = z2; }

  const int keyBase = b * 1024 + sp * 128;     // 128 keys per split
  const u16* kgb = Km + (size_t)keyBase * 512 + lane * 8;  // per-lane 16B of key row
  const u16* vgb = Vm + (size_t)keyBase * 512 + lane * 8;
  u16* wbase = lds + wave * 4096;

  // prologue: stage chunk 0 (2 keys: K rows -> [0,1024), V rows -> [1024,2048))
  async_ld16(kgb, wbase);
  async_ld16(kgb + 512, wbase + 512);
  async_ld16(vgb, wbase + 1024);
  async_ld16(vgb + 512, wbase + 1536);

#pragma unroll 1
  for (int cc = 0; cc < 64; ++cc) {
    // wait for current chunk's 4 async loads (and anything older) to land in LDS
    asm volatile("s_waitcnt vmcnt(0)" ::: "memory");
    __builtin_amdgcn_sched_barrier(0);
    const int cur = cc & 1;
    const u16* buf = wbase + cur * 2048;
    // issue next chunk's loads into the other buffer; they fly during compute below
    if (cc < 63) {
      const u16* kg = kgb + (size_t)(cc + 1) * 1024;
      const u16* vg = vgb + (size_t)(cc + 1) * 1024;
      u16* nb = wbase + (cur ^ 1) * 2048;
      async_ld16(kg, nb);
      async_ld16(kg + 512, nb + 512);
      async_ld16(vg, nb + 1024);
      async_ld16(vg + 512, nb + 1536);
    }

#pragma unroll
    for (int r = 0; r < 2; ++r) {
      const u16* krow = buf + r * 512;
      const u16* vrow = buf + 1024 + r * 512;

      // ---- cdist: packed fp16 L1 over the 32-feat slice, 4 queries
      __half2 a0[4], a1[4];
#pragma unroll
      for (int qi = 0; qi < 4; ++qi) { a0[qi] = z2; a1[qi] = z2; }
#pragma unroll
      for (int pi = 0; pi < 4; ++pi) {
        const H4 k4 = toH4(*(const int4*)(krow + grans[pi] * 8));
#pragma unroll
        for (int qi = 0; qi < 4; ++qi) {
          a0[qi] = __hadd2(a0[qi], __habs2(__hsub2(k4.a, Qh[qi][pi].a)));
          a1[qi] = __hadd2(a1[qi], __habs2(__hsub2(k4.b, Qh[qi][pi].b)));
          a0[qi] = __hadd2(a0[qi], __habs2(__hsub2(k4.c, Qh[qi][pi].c)));
          a1[qi] = __hadd2(a1[qi], __habs2(__hsub2(k4.d, Qh[qi][pi].d)));
        }
      }

      // ---- per-query: horizontal -> half-merge (xor1) -> softmax over heads
      __half2 wh[4];
#pragma unroll
      for (int qi = 0; qi < 4; ++qi) {
        const __half2 s2 = __hadd2(a0[qi], a1[qi]);
        float d8p = __half2float(__low2half(s2)) + __half2float(__high2half(s2));
        const float d8 = dpp_add_f<0xB1>(d8p);          // merge the two half-slices (lane^1)
        const float e = __expf(-0.5f * d8 * d8);        // e <= 1, no overflow
        float nrm = e;
        nrm = dpp_add_f<0x4E>(nrm);                     // lane^2
        nrm = dpp_add_f<0x141>(nrm);                    // row_half_mirror
        nrm = dpp_add_f<0x140>(nrm);                    // row_mirror
        const float w = e * __builtin_amdgcn_rcpf(nrm); // spans all 8 heads exactly once
        wh[qi] = __float2half2_rn(w);
      }

      // ---- PV: o += w * V over the slice
#pragma unroll
      for (int pi = 0; pi < 4; ++pi) {
        const H4 v4 = toH4(*(const int4*)(vrow + grans[pi] * 8));
#pragma unroll
        for (int qi = 0; qi < 4; ++qi) {
          o[qi][pi].a = __hfma2(wh[qi], v4.a, o[qi][pi].a);
          o[qi][pi].b = __hfma2(wh[qi], v4.b, o[qi][pi].b);
          o[qi][pi].c = __hfma2(wh[qi], v4.c, o[qi][pi].c);
          o[qi][pi].d = __hfma2(wh[qi], v4.d, o[qi][pi].d);
        }
      }
    }
  }

  // ---- store fp16 partial (head-major): bounce through the wave's (now dead) LDS
  // slice so global stores are fully-coalesced 1KB rows (64 lanes x contiguous 16B).
  u16* Ew = wbase;   // 2048 halfs = 4 output rows of 512, reused per qi batch
#pragma unroll
  for (int qi = 0; qi < 4; ++qi) {
    // scatter this qi's granules into LDS row (q-group)
#pragma unroll
    for (int pi = 0; pi < 4; ++pi)
      *(int4*)(Ew + qg * 512 + grans[pi] * 8) = fromH4(o[qi][pi]);
    asm volatile("s_waitcnt lgkmcnt(0)" ::: "memory");
    // linear read + coalesced store: LDS row p holds output row j0 + p + qi*4
#pragma unroll
    for (int p = 0; p < 4; ++p) {
      const int4 v = *(const int4*)(Ew + p * 512 + lane * 8);
      u16* dst = partial + (size_t)sp * (4096 * 512) + (size_t)(b * 1024 + j0 + p + qi * 4) * 512;
      *(int4*)(dst + lane * 8) = v;
    }
    asm volatile("s_waitcnt lgkmcnt(0)" ::: "memory");
  }
}

// ---------------- reduce: out_pre = bf16(sum of 8 fp16 partials) ----------------
__global__ __launch_bounds__(256) void reduce_k(const u16* __restrict__ p,
                                                u16* __restrict__ out) {
  const size_t i = ((size_t)blockIdx.x * 256 + threadIdx.x) * 8;   // granule of 8 halfs
  float s[8] = {0.f, 0.f, 0.f, 0.f, 0.f, 0.f, 0.f, 0.f};
#pragma unroll
  for (int sp = 0; sp < 8; ++sp) {
    const int4 t = *(const int4*)(p + (size_t)sp * (4096 * 512) + i);
    const __half* th = reinterpret_cast<const __half*>(&t);
#pragma unroll
    for (int j = 0; j < 8; ++j) s[j] += __half2float(th[j]);
  }
  int4 pk;
  u16* pu = reinterpret_cast<u16*>(&pk);
#pragma unroll
  for (int j = 0; j < 8; ++j) pu[j] = f2bf(s[j]);
  *(int4*)(out + i) = pk;
}

// ---------------- host ----------------
extern "C" void kernel_launch(void* const* d_in, const int* in_sizes, int n_in,
                              void* d_out, int out_size, void* d_ws, size_t ws_size,
                              hipStream_t stream) {
  (void)in_sizes; (void)n_in; (void)out_size; (void)ws_size;
  char* wsp = (char*)d_ws;
  size_t off = 0;
  auto take = [&](size_t bytes) {
    void* p = (void*)(wsp + off);
    off += ((bytes + 255) & ~(size_t)255);
    return p;
  };

  static const int wR[10] = {128, 512, 512, 128, 512, 512, 128, 512, 512, 512};
  static const int wC[10] = {512, 512, 512, 512, 512, 512, 512, 512, 512, 128};
  static const int widx[10] = {3, 5, 7, 9, 11, 13, 15, 17, 19, 21};

  u16* WT[10];
  for (int i = 0; i < 10; ++i) WT[i] = (u16*)take((size_t)wR[i] * wC[i] * 2);
  u16* a0[3]; for (int i = 0; i < 3; ++i) a0[i] = (u16*)take((size_t)4096 * 128 * 2);
  u16* h1[3]; for (int i = 0; i < 3; ++i) h1[i] = (u16*)take((size_t)4096 * 512 * 2);
  u16* h2[3]; for (int i = 0; i < 3; ++i) h2[i] = (u16*)take((size_t)4096 * 512 * 2);
  u16* partial = (u16*)take((size_t)8 * 4096 * 512 * 2);   // fp16, 8 key-splits

  TransArgs ta;
  for (int i = 0; i < 10; ++i) {
    ta.src[i] = (const float*)d_in[widx[i]];
    ta.dst[i] = WT[i];
    ta.R[i] = wR[i];
    ta.C[i] = wC[i];
  }
  hipLaunchKernelGGL(transpose_k, dim3(16, 16, 10), dim3(256), 0, stream, ta);

  // convert inputs fp32 -> bf16  (0=KEY for k-MLP, 1=QUERY for q-MLP, 2=VALUE for v-MLP)
  ConvArgs ca;
  ca.src[0] = (const float*)d_in[0]; ca.src[1] = (const float*)d_in[2]; ca.src[2] = (const float*)d_in[1];
  ca.dst[0] = a0[0]; ca.dst[1] = a0[1]; ca.dst[2] = a0[2];
  hipLaunchKernelGGL(conv_k, dim3(256, 1, 3), dim3(256), 0, stream, ca);

  // layer 1: [4096x128]@[128x512]+b, relu
  GemmArgs g1 = {};
  for (int i = 0; i < 3; ++i) g1.A[i] = a0[i];
  g1.WT[0] = WT[0]; g1.WT[1] = WT[3]; g1.WT[2] = WT[6];
  g1.bias[0] = (const float*)d_in[4]; g1.bias[1] = (const float*)d_in[10]; g1.bias[2] = (const float*)d_in[16];
  g1.C[0] = h1[0]; g1.C[1] = h1[1]; g1.C[2] = h1[2];
  hipLaunchKernelGGL(gemm128, dim3(4, 32, 3), dim3(256), 0, stream, g1, 4096, 512, 128, 1, 0, 0);

  // layer 2: [4096x512]@[512x512]+b, relu
  GemmArgs g2 = {};
  for (int i = 0; i < 3; ++i) { g2.A[i] = h1[i]; g2.C[i] = h2[i]; }
  g2.WT[0] = WT[1]; g2.WT[1] = WT[4]; g2.WT[2] = WT[7];
  g2.bias[0] = (const float*)d_in[6]; g2.bias[1] = (const float*)d_in[12]; g2.bias[2] = (const float*)d_in[18];
  hipLaunchKernelGGL(gemm128, dim3(4, 32, 3), dim3(256), 0, stream, g2, 4096, 512, 512, 1, 0, 0);

  // layer 3: -> Km,Qm,Vm fp16, HEAD-MAJOR feature layout
  GemmArgs g3 = {};
  for (int i = 0; i < 3; ++i) { g3.A[i] = h2[i]; g3.C[i] = (void*)h1[i]; }
  g3.WT[0] = WT[2]; g3.WT[1] = WT[5]; g3.WT[2] = WT[8];
  g3.bias[0] = (const float*)d_in[8]; g3.bias[1] = (const float*)d_in[14]; g3.bias[2] = (const float*)d_in[20];
  hipLaunchKernelGGL(gemm128, dim3(4, 32, 3), dim3(256), 0, stream, g3, 4096, 512, 512, 0, 2, 1);

  // fused attention (8-way key split, 16 q/wave, private async dbuf, (256,2))
  hipLaunchKernelGGL(attn_kernel, dim3(512), dim3(256), 0, stream, h1[0], h1[1], h1[2], partial);

  // reduce partials -> out_pre (bf16, head-major) in h2[0]
  hipLaunchKernelGGL(reduce_k, dim3(1024), dim3(256), 0, stream, partial, h2[0]);

  // final projection: [4096x512]@[512x128]+b -> d_out (fp32); WT[9] K-dim permuted to match
  GemmArgs g4 = {};
  g4.A[0] = h2[0]; g4.WT[0] = WT[9]; g4.bias[0] = (const float*)d_in[22]; g4.C[0] = d_out;
  hipLaunchKernelGGL(gemm128, dim3(1, 32, 1), dim3(256), 0, stream, g4, 4096, 128, 512, 0, 1, 0);
}

// Round 12
// 356.860 us; speedup vs baseline: 1.0711x; 1.0711x over previous
//
#include <hip/hip_runtime.h>
#include <hip/hip_bf16.h>
#include <hip/hip_fp16.h>

typedef unsigned short u16;
typedef __attribute__((ext_vector_type(8))) short short8;
typedef __attribute__((ext_vector_type(4))) float floatx4;

#define DEVI static __device__ __forceinline__

DEVI float bf2f(u16 b) { return __uint_as_float(((unsigned)b) << 16); }
DEVI u16 f2bf(float f) {
  __hip_bfloat16 h = __float2bfloat16(f);
  u16 u; __builtin_memcpy(&u, &h, 2); return u;
}
DEVI u16 f2h(float f) {
  __half h = __float2half(f);
  u16 u; __builtin_memcpy(&u, &h, 2); return u;
}

// async global->LDS, 16B per lane; LDS dest = wave-uniform base + lane*16
DEVI void async_ld16(const u16* g, u16* l) {
  __builtin_amdgcn_global_load_lds(
      (const __attribute__((address_space(1))) unsigned int*)g,
      (__attribute__((address_space(3))) unsigned int*)l, 16, 0, 0);
}

// DPP cross-lane add on float (VALU pipe)
template <int CTRL>
DEVI float dpp_add_f(float v) {
  int i; __builtin_memcpy(&i, &v, 4);
  int p = __builtin_amdgcn_update_dpp(0, i, CTRL, 0xF, 0xF, false);
  float pv; __builtin_memcpy(&pv, &p, 4);
  return v + pv;
}

// head-major permutation: feature f (= d*8+h) -> c' = h*64+d
DEVI int hperm(int f) { return ((f & 7) << 6) | (f >> 3); }

// 4x half2 as named fields (NO element address-taking: keeps SROA able to promote
// everything to registers -> no scratch spill; verified clean v10/v12/v14)
struct H4 { __half2 a, b, c, d; };
DEVI H4 toH4(const int4 v) { H4 r; __builtin_memcpy(&r, &v, 16); return r; }
DEVI int4 fromH4(const H4 x) { int4 r; __builtin_memcpy(&r, &x, 16); return r; }

// ---------------- weight transpose + fp32->bf16: dst[C][R] = bf16(src[R][C]^T) ----------------
struct TransArgs {
  const float* src[10];
  u16* dst[10];
  int R[10];
  int C[10];
};

__global__ __launch_bounds__(256) void transpose_k(TransArgs t) {
  const int z = blockIdx.z;
  const float* __restrict__ src = t.src[z];
  u16* __restrict__ dst = t.dst[z];
  const int R = t.R[z], C = t.C[z];
  const int c0 = blockIdx.x * 32, r0 = blockIdx.y * 32;
  if (c0 >= C || r0 >= R) return;
  __shared__ float tile[32][33];
  const int tx = threadIdx.x & 31, ty = threadIdx.x >> 5;
  for (int i = ty; i < 32; i += 8)
    tile[i][tx] = src[(size_t)(r0 + i) * C + c0 + tx];
  __syncthreads();
  for (int i = ty; i < 32; i += 8) {
    const int f = r0 + tx;
    const int fi = (z == 9) ? hperm(f) : f;
    dst[(size_t)(c0 + i) * R + fi] = f2bf(tile[tx][i]);
  }
}

// ---------------- fp32 -> bf16 convert for KEY/QUERY/VALUE ----------------
struct ConvArgs {
  const float* src[3];
  u16* dst[3];
};

__global__ __launch_bounds__(256) void conv_k(ConvArgs c) {
  const int z = blockIdx.z;
  const float* __restrict__ src = c.src[z];
  u16* __restrict__ dst = c.dst[z];
  const size_t i = ((size_t)blockIdx.x * 256 + threadIdx.x) * 8;
  const float4 f0 = *(const float4*)(src + i);
  const float4 f1 = *(const float4*)(src + i + 4);
  u16 tmp[8] = {f2bf(f0.x), f2bf(f0.y), f2bf(f0.z), f2bf(f0.w),
                f2bf(f1.x), f2bf(f1.y), f2bf(f1.z), f2bf(f1.w)};
  int4 t; __builtin_memcpy(&t, tmp, 16);
  *(int4*)(dst + i) = t;
}

// ------------- GEMM 128x128 tile, async global->LDS staging (layers 1-3) -------------
struct GemmArgs {
  const u16* A[3];
  const u16* WT[3];
  const float* bias[3];
  void* C[3];
};

__global__ __launch_bounds__(256, 3) void gemm128(GemmArgs ga, int M, int N, int K,
                                                  int relu, int c_mode, int out_perm) {
  const int z = blockIdx.z;
  const u16* __restrict__ A = ga.A[z];
  const u16* __restrict__ WT = ga.WT[z];
  const float* __restrict__ bias = ga.bias[z];
  void* __restrict__ C = ga.C[z];

  __shared__ u16 As[128 * 64];
  __shared__ u16 Bs[128 * 64];

  const int tid = threadIdx.x;
  const int lane = tid & 63;
  const int wave = tid >> 6;
  const int wm = wave >> 1, wn = wave & 1;
  const int mb = blockIdx.y, nb = blockIdx.x;

  floatx4 acc[4][4];
#pragma unroll
  for (int mi = 0; mi < 4; ++mi)
#pragma unroll
    for (int ni = 0; ni < 4; ++ni) acc[mi][ni] = floatx4{0.f, 0.f, 0.f, 0.f};

  // staging: lane covers row (lane>>3) of an 8-row strip, phys granule (lane&7);
  // global column granule = phys ^ (row&7)
  const int g = (lane & 7) ^ ((lane >> 3) & 7);
  const int srow = lane >> 3;
  const size_t aRowBase = (size_t)(mb * 128 + wave * 32 + srow) * K + g * 8;
  const size_t bRowBase = (size_t)(nb * 128 + wave * 32 + srow) * K + g * 8;

  for (int k0 = 0; k0 < K; k0 += 64) {
    __syncthreads();
#pragma unroll
    for (int it = 0; it < 4; ++it) {
      async_ld16(A + aRowBase + (size_t)it * 8 * K + k0, As + (wave * 32 + it * 8) * 64);
      async_ld16(WT + bRowBase + (size_t)it * 8 * K + k0, Bs + (wave * 32 + it * 8) * 64);
    }
    __syncthreads();
#pragma unroll
    for (int ks = 0; ks < 2; ++ks) {
      const int phys = ((ks * 4 + (lane >> 4)) ^ (lane & 7)) * 8;
      short8 af[4], bf[4];
#pragma unroll
      for (int i = 0; i < 4; ++i) {
        const int m = wm * 64 + i * 16 + (lane & 15);
        const int n = wn * 64 + i * 16 + (lane & 15);
        af[i] = *(const short8*)(As + m * 64 + phys);
        bf[i] = *(const short8*)(Bs + n * 64 + phys);
      }
#pragma unroll
      for (int mi = 0; mi < 4; ++mi)
#pragma unroll
        for (int ni = 0; ni < 4; ++ni)
          acc[mi][ni] = __builtin_amdgcn_mfma_f32_16x16x32_bf16(af[mi], bf[ni], acc[mi][ni], 0, 0, 0);
    }
  }

  // C/D layout: col = lane&15, row = (lane>>4)*4 + reg
#pragma unroll
  for (int mi = 0; mi < 4; ++mi)
#pragma unroll
    for (int ni = 0; ni < 4; ++ni) {
      const int col = nb * 128 + wn * 64 + ni * 16 + (lane & 15);
      const float bv = bias[col];
      const int colw = out_perm ? hperm(col) : col;
      const floatx4 v = acc[mi][ni];
#pragma unroll
      for (int r = 0; r < 4; ++r) {
        const int row = mb * 128 + wm * 64 + mi * 16 + (lane >> 4) * 4 + r;
        float x = v[r] + bv;
        if (relu) x = fmaxf(x, 0.f);
        if (c_mode == 1)      ((float*)C)[(size_t)row * N + colw] = x;
        else if (c_mode == 2) ((u16*)C)[(size_t)row * N + colw] = f2h(x);
        else                  ((u16*)C)[(size_t)row * N + colw] = f2bf(x);
      }
    }
}

// -------- fused attention v14 (BEST measured: 186.5us): 16q/wave, private async dbuf, (256,3) --------
// v15's (256,2)+sp8 experiment regressed (208us, occupancy 19.7%, VGPR still 80) ->
// allocator keeps state in AGPR side regardless of bounds; sp=16 grid restored.
__global__ __launch_bounds__(256, 3) void attn_kernel(const u16* __restrict__ Km,
                                                      const u16* __restrict__ Qm,
                                                      const u16* __restrict__ Vm,
                                                      u16* __restrict__ partial) {
  // per wave: 2 buffers x (2 K-rows + 2 V-rows) = 4096 halfs = 8KB; block = 32KB
  __shared__ alignas(16) u16 lds[4 * 4096];

  const int tid = threadIdx.x;
  const int lane = tid & 63;
  const int wave = tid >> 6;
  const int wid = blockIdx.x * 4 + wave;      // 0..4095
  const int qt = wid & 63;                    // 64 q-tiles of 16 rows
  const int sp = (wid >> 6) & 15;
  const int b = wid >> 10;
  const int j0 = qt * 16;

  const int qg = lane >> 4;
  const int h = (lane >> 1) & 7;
  const int half = lane & 1;

  int grans[4];
#pragma unroll
  for (int pi = 0; pi < 4; ++pi)
    grans[pi] = h * 8 + half * 4 + ((pi + h) & 3);

  // Q into registers: 4 queries x 4 granules (rotated order), H4 fields
  H4 Qh[4][4];
#pragma unroll
  for (int qi = 0; qi < 4; ++qi) {
    const u16* qrow = Qm + (size_t)(b * 1024 + j0 + qg + qi * 4) * 512;
#pragma unroll
    for (int pi = 0; pi < 4; ++pi)
      Qh[qi][pi] = toH4(*(const int4*)(qrow + grans[pi] * 8));
  }

  const __half2 z2 = __float2half2_rn(0.f);
  H4 o[4][4];
#pragma unroll
  for (int qi = 0; qi < 4; ++qi)
#pragma unroll
    for (int pi = 0; pi < 4; ++pi) { o[qi][pi].a = z2; o[qi][pi].b = z2; o[qi][pi].c = z2; o[qi][pi].d = z2; }

  const int keyBase = b * 1024 + sp * 64;
  const u16* kgb = Km + (size_t)keyBase * 512 + lane * 8;  // per-lane 16B of key row
  const u16* vgb = Vm + (size_t)keyBase * 512 + lane * 8;
  u16* wbase = lds + wave * 4096;

  // prologue: stage chunk 0 (2 keys: K rows -> [0,1024), V rows -> [1024,2048))
  async_ld16(kgb, wbase);
  async_ld16(kgb + 512, wbase + 512);
  async_ld16(vgb, wbase + 1024);
  async_ld16(vgb + 512, wbase + 1536);

#pragma unroll 1
  for (int cc = 0; cc < 32; ++cc) {
    // wait for current chunk's 4 async loads (and anything older) to land in LDS
    asm volatile("s_waitcnt vmcnt(0)" ::: "memory");
    __builtin_amdgcn_sched_barrier(0);
    const int cur = cc & 1;
    const u16* buf = wbase + cur * 2048;
    // issue next chunk's loads into the other buffer; they fly during compute below
    if (cc < 31) {
      const u16* kg = kgb + (size_t)(cc + 1) * 1024;
      const u16* vg = vgb + (size_t)(cc + 1) * 1024;
      u16* nb = wbase + (cur ^ 1) * 2048;
      async_ld16(kg, nb);
      async_ld16(kg + 512, nb + 512);
      async_ld16(vg, nb + 1024);
      async_ld16(vg + 512, nb + 1536);
    }

#pragma unroll
    for (int r = 0; r < 2; ++r) {
      const u16* krow = buf + r * 512;
      const u16* vrow = buf + 1024 + r * 512;

      // ---- cdist: packed fp16 L1 over the 32-feat slice, 4 queries
      __half2 a0[4], a1[4];
#pragma unroll
      for (int qi = 0; qi < 4; ++qi) { a0[qi] = z2; a1[qi] = z2; }
#pragma unroll
      for (int pi = 0; pi < 4; ++pi) {
        const H4 k4 = toH4(*(const int4*)(krow + grans[pi] * 8));
#pragma unroll
        for (int qi = 0; qi < 4; ++qi) {
          a0[qi] = __hadd2(a0[qi], __habs2(__hsub2(k4.a, Qh[qi][pi].a)));
          a1[qi] = __hadd2(a1[qi], __habs2(__hsub2(k4.b, Qh[qi][pi].b)));
          a0[qi] = __hadd2(a0[qi], __habs2(__hsub2(k4.c, Qh[qi][pi].c)));
          a1[qi] = __hadd2(a1[qi], __habs2(__hsub2(k4.d, Qh[qi][pi].d)));
        }
      }

      // ---- per-query: horizontal -> half-merge (xor1) -> softmax over heads
      __half2 wh[4];
#pragma unroll
      for (int qi = 0; qi < 4; ++qi) {
        const __half2 s2 = __hadd2(a0[qi], a1[qi]);
        float d8p = __half2float(__low2half(s2)) + __half2float(__high2half(s2));
        const float d8 = dpp_add_f<0xB1>(d8p);          // merge the two half-slices (lane^1)
        const float e = __expf(-0.5f * d8 * d8);        // e <= 1, no overflow
        float nrm = e;
        nrm = dpp_add_f<0x4E>(nrm);                     // lane^2
        nrm = dpp_add_f<0x141>(nrm);                    // row_half_mirror
        nrm = dpp_add_f<0x140>(nrm);                    // row_mirror
        const float w = e * __builtin_amdgcn_rcpf(nrm); // spans all 8 heads exactly once
        wh[qi] = __float2half2_rn(w);
      }

      // ---- PV: o += w * V over the slice
#pragma unroll
      for (int pi = 0; pi < 4; ++pi) {
        const H4 v4 = toH4(*(const int4*)(vrow + grans[pi] * 8));
#pragma unroll
        for (int qi = 0; qi < 4; ++qi) {
          o[qi][pi].a = __hfma2(wh[qi], v4.a, o[qi][pi].a);
          o[qi][pi].b = __hfma2(wh[qi], v4.b, o[qi][pi].b);
          o[qi][pi].c = __hfma2(wh[qi], v4.c, o[qi][pi].c);
          o[qi][pi].d = __hfma2(wh[qi], v4.d, o[qi][pi].d);
        }
      }
    }
  }

  // ---- store fp16 partial (head-major): bounce through the wave's (now dead) LDS
  // slice so global stores are fully-coalesced 1KB rows (64 lanes x contiguous 16B).
  u16* Ew = wbase;   // 2048 halfs = 4 output rows of 512, reused per qi batch
#pragma unroll
  for (int qi = 0; qi < 4; ++qi) {
    // scatter this qi's granules into LDS row (q-group)
#pragma unroll
    for (int pi = 0; pi < 4; ++pi)
      *(int4*)(Ew + qg * 512 + grans[pi] * 8) = fromH4(o[qi][pi]);
    asm volatile("s_waitcnt lgkmcnt(0)" ::: "memory");
    // linear read + coalesced store: LDS row p holds output row j0 + p + qi*4
#pragma unroll
    for (int p = 0; p < 4; ++p) {
      const int4 v = *(const int4*)(Ew + p * 512 + lane * 8);
      u16* dst = partial + (size_t)sp * (4096 * 512) + (size_t)(b * 1024 + j0 + p + qi * 4) * 512;
      *(int4*)(dst + lane * 8) = v;
    }
    asm volatile("s_waitcnt lgkmcnt(0)" ::: "memory");
  }
}

// -------- final projection, fused 16-partial reduce + split-K, atomic fp32 out --------
// Replaces reduce_k (64MB read pass + dispatch) AND the 32-block g4 (12.5% machine).
// Grid (8 kc, 32 mb) = 256 blocks; each stages A by summing the 16 fp16 partials in
// fp32 -> bf16 (identical rounding to the old reduce_k->bf16 path) into the same
// xor-swizzled LDS layout, single 64-wide K-step, atomicAdd fp32 into pre-zeroed out.
// Bias added by kc==0 blocks only.
__global__ __launch_bounds__(256, 3) void gemm_final(const u16* __restrict__ P,
                                                     const u16* __restrict__ WT9,
                                                     const float* __restrict__ bias,
                                                     float* __restrict__ out) {
  __shared__ u16 As[128 * 64];
  __shared__ u16 Bs[128 * 64];

  const int tid = threadIdx.x;
  const int lane = tid & 63;
  const int wave = tid >> 6;
  const int wm = wave >> 1, wn = wave & 1;
  const int mb = blockIdx.y;
  const int kc = blockIdx.x;            // 8 K-chunks of 64
  const int k0 = kc * 64;

  const int g = (lane & 7) ^ ((lane >> 3) & 7);
  const int srow = lane >> 3;

  // stage B (output cols 0..127) via async, K=512
  const size_t bRowBase = (size_t)(wave * 32 + srow) * 512 + g * 8;
#pragma unroll
  for (int it = 0; it < 4; ++it)
    async_ld16(WT9 + bRowBase + (size_t)it * 8 * 512 + k0, Bs + (wave * 32 + it * 8) * 64);

  // stage A: sum 16 fp16 partials -> bf16, same swizzled layout (lane writes lane*16B)
#pragma unroll
  for (int it = 0; it < 4; ++it) {
    const size_t gaddr = (size_t)(mb * 128 + wave * 32 + it * 8 + srow) * 512 + k0 + g * 8;
    float s[8] = {0.f, 0.f, 0.f, 0.f, 0.f, 0.f, 0.f, 0.f};
#pragma unroll
    for (int sp = 0; sp < 16; ++sp) {
      const int4 t = *(const int4*)(P + (size_t)sp * (4096 * 512) + gaddr);
      const __half* th = reinterpret_cast<const __half*>(&t);
#pragma unroll
      for (int j = 0; j < 8; ++j) s[j] += __half2float(th[j]);
    }
    u16 tmp[8];
#pragma unroll
    for (int j = 0; j < 8; ++j) tmp[j] = f2bf(s[j]);
    int4 pk; __builtin_memcpy(&pk, tmp, 16);
    *(int4*)(As + (wave * 32 + it * 8) * 64 + lane * 8) = pk;
  }
  __syncthreads();   // drains async B (vmcnt) + A ds_writes (lgkmcnt)

  floatx4 acc[4][4];
#pragma unroll
  for (int mi = 0; mi < 4; ++mi)
#pragma unroll
    for (int ni = 0; ni < 4; ++ni) acc[mi][ni] = floatx4{0.f, 0.f, 0.f, 0.f};

#pragma unroll
  for (int ks = 0; ks < 2; ++ks) {
    const int phys = ((ks * 4 + (lane >> 4)) ^ (lane & 7)) * 8;
    short8 af[4], bf[4];
#pragma unroll
    for (int i = 0; i < 4; ++i) {
      const int m = wm * 64 + i * 16 + (lane & 15);
      const int n = wn * 64 + i * 16 + (lane & 15);
      af[i] = *(const short8*)(As + m * 64 + phys);
      bf[i] = *(const short8*)(Bs + n * 64 + phys);
    }
#pragma unroll
    for (int mi = 0; mi < 4; ++mi)
#pragma unroll
      for (int ni = 0; ni < 4; ++ni)
        acc[mi][ni] = __builtin_amdgcn_mfma_f32_16x16x32_bf16(af[mi], bf[ni], acc[mi][ni], 0, 0, 0);
  }

  // epilogue: atomicAdd fp32 (out pre-zeroed); bias once via kc==0
#pragma unroll
  for (int mi = 0; mi < 4; ++mi)
#pragma unroll
    for (int ni = 0; ni < 4; ++ni) {
      const int col = wn * 64 + ni * 16 + (lane & 15);
      const float bv = (kc == 0) ? bias[col] : 0.f;
      const floatx4 v = acc[mi][ni];
#pragma unroll
      for (int r = 0; r < 4; ++r) {
        const int row = mb * 128 + wm * 64 + mi * 16 + (lane >> 4) * 4 + r;
        atomicAdd(&out[(size_t)row * 128 + col], v[r] + bv);
      }
    }
}

// ---------------- host ----------------
extern "C" void kernel_launch(void* const* d_in, const int* in_sizes, int n_in,
                              void* d_out, int out_size, void* d_ws, size_t ws_size,
                              hipStream_t stream) {
  (void)in_sizes; (void)n_in; (void)out_size; (void)ws_size;
  char* wsp = (char*)d_ws;
  size_t off = 0;
  auto take = [&](size_t bytes) {
    void* p = (void*)(wsp + off);
    off += ((bytes + 255) & ~(size_t)255);
    return p;
  };

  static const int wR[10] = {128, 512, 512, 128, 512, 512, 128, 512, 512, 512};
  static const int wC[10] = {512, 512, 512, 512, 512, 512, 512, 512, 512, 128};
  static const int widx[10] = {3, 5, 7, 9, 11, 13, 15, 17, 19, 21};

  u16* WT[10];
  for (int i = 0; i < 10; ++i) WT[i] = (u16*)take((size_t)wR[i] * wC[i] * 2);
  u16* a0[3]; for (int i = 0; i < 3; ++i) a0[i] = (u16*)take((size_t)4096 * 128 * 2);
  u16* h1[3]; for (int i = 0; i < 3; ++i) h1[i] = (u16*)take((size_t)4096 * 512 * 2);
  u16* h2[3]; for (int i = 0; i < 3; ++i) h2[i] = (u16*)take((size_t)4096 * 512 * 2);
  u16* partial = (u16*)take((size_t)16 * 4096 * 512 * 2);   // fp16, 16 key-splits

  TransArgs ta;
  for (int i = 0; i < 10; ++i) {
    ta.src[i] = (const float*)d_in[widx[i]];
    ta.dst[i] = WT[i];
    ta.R[i] = wR[i];
    ta.C[i] = wC[i];
  }
  hipLaunchKernelGGL(transpose_k, dim3(16, 16, 10), dim3(256), 0, stream, ta);

  // convert inputs fp32 -> bf16  (0=KEY for k-MLP, 1=QUERY for q-MLP, 2=VALUE for v-MLP)
  ConvArgs ca;
  ca.src[0] = (const float*)d_in[0]; ca.src[1] = (const float*)d_in[2]; ca.src[2] = (const float*)d_in[1];
  ca.dst[0] = a0[0]; ca.dst[1] = a0[1]; ca.dst[2] = a0[2];
  hipLaunchKernelGGL(conv_k, dim3(256, 1, 3), dim3(256), 0, stream, ca);

  // layer 1: [4096x128]@[128x512]+b, relu
  GemmArgs g1 = {};
  for (int i = 0; i < 3; ++i) g1.A[i] = a0[i];
  g1.WT[0] = WT[0]; g1.WT[1] = WT[3]; g1.WT[2] = WT[6];
  g1.bias[0] = (const float*)d_in[4]; g1.bias[1] = (const float*)d_in[10]; g1.bias[2] = (const float*)d_in[16];
  g1.C[0] = h1[0]; g1.C[1] = h1[1]; g1.C[2] = h1[2];
  hipLaunchKernelGGL(gemm128, dim3(4, 32, 3), dim3(256), 0, stream, g1, 4096, 512, 128, 1, 0, 0);

  // layer 2: [4096x512]@[512x512]+b, relu
  GemmArgs g2 = {};
  for (int i = 0; i < 3; ++i) { g2.A[i] = h1[i]; g2.C[i] = h2[i]; }
  g2.WT[0] = WT[1]; g2.WT[1] = WT[4]; g2.WT[2] = WT[7];
  g2.bias[0] = (const float*)d_in[6]; g2.bias[1] = (const float*)d_in[12]; g2.bias[2] = (const float*)d_in[18];
  hipLaunchKernelGGL(gemm128, dim3(4, 32, 3), dim3(256), 0, stream, g2, 4096, 512, 512, 1, 0, 0);

  // layer 3: -> Km,Qm,Vm fp16, HEAD-MAJOR feature layout
  GemmArgs g3 = {};
  for (int i = 0; i < 3; ++i) { g3.A[i] = h2[i]; g3.C[i] = (void*)h1[i]; }
  g3.WT[0] = WT[2]; g3.WT[1] = WT[5]; g3.WT[2] = WT[8];
  g3.bias[0] = (const float*)d_in[8]; g3.bias[1] = (const float*)d_in[14]; g3.bias[2] = (const float*)d_in[20];
  hipLaunchKernelGGL(gemm128, dim3(4, 32, 3), dim3(256), 0, stream, g3, 4096, 512, 512, 0, 2, 1);

  // fused attention (16-way key split, 16 q/wave, private async dbuf, (256,3)) -> fp16 partials
  hipLaunchKernelGGL(attn_kernel, dim3(1024), dim3(256), 0, stream, h1[0], h1[1], h1[2], partial);

  // final projection with fused 16-partial reduce + split-K(8), atomic fp32 accumulate
  hipMemsetAsync(d_out, 0, (size_t)4096 * 128 * sizeof(float), stream);
  hipLaunchKernelGGL(gemm_final, dim3(8, 32), dim3(256), 0, stream,
                     partial, WT[9], (const float*)d_in[22], (float*)d_out);
}